// Round 1
// baseline (379.772 us; speedup 1.0000x reference)
//
#include <hip/hip_runtime.h>
#include <hip/hip_bf16.h>
#include <stdint.h>

// TT config (fixed by the problem)
#define NT 4
#define PP 100           // P0 == P1 == P2 == 100
#define RK 32            // interior TT ranks
// tT slice layout per (tab,i0,i1): [s=0..31][ab=0..15] bf16  -> 512 elems, 1 KB
// tT total: 4*100*100 slices * 1KB = 40.96 MB (lives in d_ws)

__device__ __forceinline__ uint32_t f2bf(float f) {
    union { float f; uint32_t u; } v; v.f = f;
    uint32_t u = v.u;
    return (u + 0x7fffu + ((u >> 16) & 1u)) >> 16;   // RNE to bf16
}

// ---------------- Phase 1: t[tab,i0,i1] = c0[tab,i0] @ c1[tab,i1] ----------------
// grid: 4 tables * 100 i1 * 4 i0-chunks = 1600 blocks, 256 threads.
// Thread task: (i0 within chunk of 32, s-group of 4). Computes all 16 ab for 4 s.
__global__ __launch_bounds__(256, 4)
void tt_phase1(const float* __restrict__ c0g, const float* __restrict__ c1g,
               unsigned short* __restrict__ tT) {
    __shared__ float c0s[32 * 132];   // 32 i0 rows, 128 floats padded to 132 (bank-conflict-free)
    __shared__ float c1s[4096];       // c1[tab,i1] slice: [r=32][b=4][s=32]

    int b = blockIdx.x;
    int tab   = b / 400;
    int rem   = b % 400;
    int i1    = rem / 4;
    int chunk = rem % 4;
    int i0_base = chunk * 32;
    int tid = threadIdx.x;

    // stage c1 slice (16 KB)
    const float4* c1p = (const float4*)(c1g + (size_t)(tab * PP + i1) * 4096);
    float4* c1sv = (float4*)c1s;
    #pragma unroll
    for (int it = 0; it < 4; ++it) c1sv[tid + 256 * it] = c1p[tid + 256 * it];

    // stage 32 c0 rows (clamped at 100)
    #pragma unroll
    for (int it = 0; it < 4; ++it) {
        int tt  = tid + 256 * it;     // 0..1023
        int i0l = tt >> 5;            // 0..31
        int v   = tt & 31;            // float4 within 128-float row
        int i0  = i0_base + i0l; if (i0 > PP - 1) i0 = PP - 1;
        const float4* src = (const float4*)(c0g + (size_t)(tab * PP + i0) * 128);
        *(float4*)&c0s[i0l * 132 + v * 4] = src[v];
    }
    __syncthreads();

    int i0l = tid >> 3;               // 0..31
    int sg  = tid & 7;                // s-group: s = sg*4 + q
    int i0  = i0_base + i0l;
    if (i0 >= PP) return;

    float acc[4][4][4] = {};          // [a][b][q]
    #pragma unroll
    for (int k = 0; k < 32; ++k) {
        float av[4];
        #pragma unroll
        for (int a = 0; a < 4; ++a) av[a] = c0s[i0l * 132 + a * 32 + k];
        #pragma unroll
        for (int bb = 0; bb < 4; ++bb) {
            float4 bv = *(const float4*)&c1s[k * 128 + bb * 32 + sg * 4];
            #pragma unroll
            for (int a = 0; a < 4; ++a) {
                acc[a][bb][0] += av[a] * bv.x;
                acc[a][bb][1] += av[a] * bv.y;
                acc[a][bb][2] += av[a] * bv.z;
                acc[a][bb][3] += av[a] * bv.w;
            }
        }
    }

    size_t combo = (size_t)tab * 10000 + (size_t)i0 * 100 + (size_t)i1;
    char* base = (char*)tT + combo * 1024;
    #pragma unroll
    for (int q = 0; q < 4; ++q) {
        int s = sg * 4 + q;
        uint32_t w[8];
        #pragma unroll
        for (int j = 0; j < 8; ++j) {
            int ab0 = 2 * j, ab1 = 2 * j + 1;
            uint32_t lo = f2bf(acc[ab0 >> 2][ab0 & 3][q]);
            uint32_t hi = f2bf(acc[ab1 >> 2][ab1 & 3][q]);
            w[j] = lo | (hi << 16);
        }
        uint4* dst = (uint4*)(base + s * 32);
        dst[0] = make_uint4(w[0], w[1], w[2], w[3]);
        dst[1] = make_uint4(w[4], w[5], w[6], w[7]);
    }
}

// ---------------- Phase 2: gather tT + contract with c2 + pool ----------------
// 1 wave per bag; block = 4 waves = 4 bags. Lane = (sub = lookup slot 0..3, sg = s-pair 0..15).
// Each lane accumulates partials of ALL 64 outputs over its (sub, s-pair) slice;
// log-fold shuffle reduction leaves output[lane] in acc[0].
__global__ __launch_bounds__(256, 4)
void tt_phase2(const int* __restrict__ indices, const int* __restrict__ offsets,
               const unsigned short* __restrict__ tT, const float* __restrict__ c2g,
               float* __restrict__ out, int bags_per_table, int B) {
    int lane = threadIdx.x & 63;
    int wv   = threadIdx.x >> 6;
    int bag  = blockIdx.x * 4 + wv;
    if (bag >= B) return;
    int sub = lane >> 4;
    int sg  = lane & 15;

    int start = offsets[bag];
    int end   = offsets[bag + 1];
    int tab   = bag / bags_per_table;

    float acc[64];
    #pragma unroll
    for (int j = 0; j < 64; ++j) acc[j] = 0.f;

    for (int n = start + sub; n < end; n += 4) {
        uint32_t idx = (uint32_t)indices[n];
        uint32_t i0  = idx / 10000u;
        uint32_t r1  = idx - i0 * 10000u;
        uint32_t i1  = r1 / 100u;
        uint32_t i2  = r1 - i1 * 100u;

        size_t combo = (size_t)tab * 10000 + (size_t)i0 * 100 + (size_t)i1;
        const uint4* tp = (const uint4*)((const char*)tT + combo * 1024 + sg * 64);
        uint4 t0 = tp[0], t1 = tp[1], t2 = tp[2], t3 = tp[3];   // s=2sg row (32B) then s=2sg+1 row

        const float4* cp = (const float4*)(c2g + ((size_t)tab * PP + i2) * 128 + sg * 8);
        float4 ce = cp[0];   // c2[2sg][0..3]
        float4 co = cp[1];   // c2[2sg+1][0..3]

        uint32_t se[8] = {t0.x, t0.y, t0.z, t0.w, t1.x, t1.y, t1.z, t1.w};
        uint32_t so[8] = {t2.x, t2.y, t2.z, t2.w, t3.x, t3.y, t3.z, t3.w};
        #pragma unroll
        for (int j = 0; j < 8; ++j) {
            float e0 = __uint_as_float(se[j] << 16);
            float e1 = __uint_as_float(se[j] & 0xffff0000u);
            float o0 = __uint_as_float(so[j] << 16);
            float o1 = __uint_as_float(so[j] & 0xffff0000u);
            int b0 = (2 * j) * 4, b1 = (2 * j + 1) * 4;
            acc[b0 + 0] += e0 * ce.x + o0 * co.x;
            acc[b0 + 1] += e0 * ce.y + o0 * co.y;
            acc[b0 + 2] += e0 * ce.z + o0 * co.z;
            acc[b0 + 3] += e0 * ce.w + o0 * co.w;
            acc[b1 + 0] += e1 * ce.x + o1 * co.x;
            acc[b1 + 1] += e1 * ce.y + o1 * co.y;
            acc[b1 + 2] += e1 * ce.z + o1 * co.z;
            acc[b1 + 3] += e1 * ce.w + o1 * co.w;
        }
    }

    // fold-reduce: sum acc[j] across all 64 lanes; lane l ends with output l in acc[0]
    #pragma unroll
    for (int m = 32; m >= 1; m >>= 1) {
        bool up = (lane & m) != 0;
        #pragma unroll
        for (int j = 0; j < m; ++j) {
            float lo = acc[j], hi = acc[j + m];
            float send = up ? lo : hi;
            float recv = __shfl_xor(send, m, 64);
            acc[j] = (up ? hi : lo) + recv;
        }
    }
    out[(size_t)bag * 64 + lane] = acc[0];
}

extern "C" void kernel_launch(void* const* d_in, const int* in_sizes, int n_in,
                              void* d_out, int out_size, void* d_ws, size_t ws_size,
                              hipStream_t stream) {
    const int*   indices = (const int*)d_in[0];
    const int*   offsets = (const int*)d_in[1];
    const float* c0      = (const float*)d_in[2];
    const float* c1      = (const float*)d_in[3];
    const float* c2      = (const float*)d_in[4];
    float* out = (float*)d_out;

    int B = in_sizes[1] - 1;              // 32768 bags
    int bags_per_table = B / NT;          // 8192

    unsigned short* tT = (unsigned short*)d_ws;   // needs 40.96 MB

    tt_phase1<<<dim3(NT * PP * 4), dim3(256), 0, stream>>>(c0, c1, tT);
    tt_phase2<<<dim3((B + 3) / 4), dim3(256), 0, stream>>>(indices, offsets, tT, c2, out,
                                                           bags_per_table, B);
}

// Round 2
// 278.822 us; speedup vs baseline: 1.3621x; 1.3621x over previous
//
#include <hip/hip_runtime.h>
#include <stdint.h>

#define NT 4
#define PP 100

// tT slice layout per combo (tab,i0,i1), 1 KB:
//   addr(k, ab) = k*256 + ab*16, holding bf16 t[ab][s = 8k .. 8k+7]
//   (ab = a*4+b, a,b in [0,4); s in [0,32))

__device__ __forceinline__ uint32_t f2bf(float f) {
    union { float f; uint32_t u; } v; v.f = f;
    uint32_t u = v.u;
    return (u + 0x7fffu + ((u >> 16) & 1u)) >> 16;   // RNE to bf16
}

// ---------------- Phase 1: t[tab,i0,i1] = c0[tab,i0] @ c1[tab,i1] ----------------
// grid: 4 tab * 100 i1 * 7 i0-chunks(16) = 2800 blocks, 256 threads.
// thread (i0l 0..15, ab 0..15): computes t[ab][s=0..31] (32 FMA x 32 r), stores
// 4 x 16B chunks -> per store instr: 4 slices x 16 lanes x 16 B = aligned 256 B runs.
__global__ __launch_bounds__(256, 4)
void tt_phase1(const float* __restrict__ c0g, const float* __restrict__ c1g,
               unsigned short* __restrict__ tT) {
    __shared__ float c1s[32 * 132];   // [r][b*32+s], row stride 132 (pad)
    __shared__ float c0t[16 * 132];   // [i0l][r*4+a], row stride 132 (pad)

    int blk = blockIdx.x;
    int tab   = blk / 700;
    int rem   = blk % 700;
    int i1    = rem / 7;
    int chunk = rem % 7;
    int i0_base = chunk * 16;
    int tid = threadIdx.x;

    // stage c1 slice (16 KB), padded rows
    const float4* c1p = (const float4*)(c1g + (size_t)(tab * PP + i1) * 4096);
    #pragma unroll
    for (int it = 0; it < 4; ++it) {
        int f = tid + 256 * it;          // float4 id 0..1023
        int r = f >> 5, x4 = f & 31;
        *(float4*)&c1s[r * 132 + x4 * 4] = c1p[f];
    }
    // stage c0 rows transposed: c0t[i0l][r*4+a] = c0[i0][a*32+r]
    #pragma unroll
    for (int it = 0; it < 8; ++it) {
        int f = tid + 256 * it;          // 0..2047
        int i0l = f >> 7;
        int x   = f & 127;               // a*32 + r
        int a = x >> 5, r = x & 31;
        int i0 = i0_base + i0l; if (i0 > PP - 1) i0 = PP - 1;
        c0t[i0l * 132 + r * 4 + a] = c0g[(size_t)(tab * PP + i0) * 128 + x];
    }
    __syncthreads();

    int i0l = tid >> 4;                  // 0..15
    int ab  = tid & 15;
    int a = ab >> 2, bq = ab & 3;
    int i0 = i0_base + i0l;

    float4 acc[8] = {};                  // s = 0..31 as 8 float4
    #pragma unroll
    for (int r = 0; r < 32; ++r) {
        float av = c0t[i0l * 132 + r * 4 + a];
        const float* crow = &c1s[r * 132 + bq * 32];
        #pragma unroll
        for (int so = 0; so < 8; ++so) {
            float4 bv = *(const float4*)(crow + so * 4);
            acc[so].x += av * bv.x; acc[so].y += av * bv.y;
            acc[so].z += av * bv.z; acc[so].w += av * bv.w;
        }
    }

    if (i0 < PP) {
        size_t combo = (size_t)tab * 10000 + (size_t)i0 * 100 + (size_t)i1;
        char* base = (char*)tT + combo * 1024 + (size_t)ab * 16;
        #pragma unroll
        for (int k = 0; k < 4; ++k) {
            float4 p0 = acc[2 * k], p1 = acc[2 * k + 1];
            uint4 w;
            w.x = f2bf(p0.x) | (f2bf(p0.y) << 16);
            w.y = f2bf(p0.z) | (f2bf(p0.w) << 16);
            w.z = f2bf(p1.x) | (f2bf(p1.y) << 16);
            w.w = f2bf(p1.z) | (f2bf(p1.w) << 16);
            *(uint4*)(base + k * 256) = w;
        }
    }
}

// ---------------- Phase 2: gather tT + contract with c2 + pool ----------------
__device__ __forceinline__ void mac_pair(uint32_t u, const float4* __restrict__ cs, int s0,
                                         float& a0, float& a1, float& a2, float& a3) {
    float e0 = __uint_as_float(u << 16);          // bf16 s0
    float e1 = __uint_as_float(u & 0xffff0000u);  // bf16 s0+1
    float4 ca = cs[s0], cb2 = cs[s0 + 1];
    a0 += e0 * ca.x + e1 * cb2.x;
    a1 += e0 * ca.y + e1 * cb2.y;
    a2 += e0 * ca.z + e1 * cb2.z;
    a3 += e0 * ca.w + e1 * cb2.w;
}

// 1 wave per bag, 4 waves/block. lane = (sub 0..3, ab 0..15).
// Lane owns output row ab (4 floats). All 16 tT dwordx4 loads issued up-front.
// c2[s] float4 are broadcast reads (16 lanes same addr) from the 200 KB L1/L2-hot table.
__global__ __launch_bounds__(256, 4)
void tt_phase2(const int* __restrict__ indices, const int* __restrict__ offsets,
               const unsigned short* __restrict__ tT, const float* __restrict__ c2g,
               float* __restrict__ out, int bags_per_table, int B) {
    int lane = threadIdx.x & 63;
    int wv   = threadIdx.x >> 6;
    int bag  = blockIdx.x * 4 + wv;
    if (bag >= B) return;
    int sub = lane >> 4;
    int ab  = lane & 15;
    int tab = bag / bags_per_table;
    int start = offsets[bag];

    const float4* c2base = (const float4*)(c2g + (size_t)tab * PP * 128);

    size_t tb[4];
    const float4* cb[4];
    #pragma unroll
    for (int j = 0; j < 4; ++j) {
        uint32_t idx = (uint32_t)indices[start + j * 4 + sub];
        uint32_t i0 = idx / 10000u;
        uint32_t r1 = idx - i0 * 10000u;
        uint32_t i1 = r1 / 100u;
        uint32_t i2 = r1 - i1 * 100u;
        tb[j] = ((size_t)tab * 10000u + i0 * 100u + i1) * 1024 + (size_t)ab * 16;
        cb[j] = c2base + (size_t)i2 * 32;
    }

    // issue all 16 tT loads (4 chunks x 4 lookups) before consuming anything
    uint4 tq[4][4];
    #pragma unroll
    for (int j = 0; j < 4; ++j) {
        const uint4* tp = (const uint4*)((const char*)tT + tb[j]);
        tq[j][0] = tp[0];
        tq[j][1] = tp[16];
        tq[j][2] = tp[32];
        tq[j][3] = tp[48];
    }

    float a0 = 0.f, a1 = 0.f, a2 = 0.f, a3 = 0.f;
    #pragma unroll
    for (int j = 0; j < 4; ++j) {
        #pragma unroll
        for (int k = 0; k < 4; ++k) {
            uint4 t = tq[j][k];
            mac_pair(t.x, cb[j], 8 * k + 0, a0, a1, a2, a3);
            mac_pair(t.y, cb[j], 8 * k + 2, a0, a1, a2, a3);
            mac_pair(t.z, cb[j], 8 * k + 4, a0, a1, a2, a3);
            mac_pair(t.w, cb[j], 8 * k + 6, a0, a1, a2, a3);
        }
    }

    // reduce partial sums across the 4 sub lanes (lane bits 4,5)
    a0 += __shfl_xor(a0, 16, 64);  a0 += __shfl_xor(a0, 32, 64);
    a1 += __shfl_xor(a1, 16, 64);  a1 += __shfl_xor(a1, 32, 64);
    a2 += __shfl_xor(a2, 16, 64);  a2 += __shfl_xor(a2, 32, 64);
    a3 += __shfl_xor(a3, 16, 64);  a3 += __shfl_xor(a3, 32, 64);

    if (sub == 0) {
        float4 o; o.x = a0; o.y = a1; o.z = a2; o.w = a3;
        ((float4*)(out + (size_t)bag * 64))[ab] = o;   // 16 lanes x 16 B contiguous
    }
}

extern "C" void kernel_launch(void* const* d_in, const int* in_sizes, int n_in,
                              void* d_out, int out_size, void* d_ws, size_t ws_size,
                              hipStream_t stream) {
    const int*   indices = (const int*)d_in[0];
    const int*   offsets = (const int*)d_in[1];
    const float* c0      = (const float*)d_in[2];
    const float* c1      = (const float*)d_in[3];
    const float* c2      = (const float*)d_in[4];
    float* out = (float*)d_out;

    int B = in_sizes[1] - 1;              // 32768 bags
    int bags_per_table = B / NT;          // 8192

    unsigned short* tT = (unsigned short*)d_ws;   // 40.96 MB

    tt_phase1<<<dim3(NT * PP * 7), dim3(256), 0, stream>>>(c0, c1, tT);
    tt_phase2<<<dim3((B + 3) / 4), dim3(256), 0, stream>>>(indices, offsets, tT, c2, out,
                                                           bags_per_table, B);
}

// Round 3
// 166.491 us; speedup vs baseline: 2.2810x; 1.6747x over previous
//
#include <hip/hip_runtime.h>
#include <stdint.h>

#define NT 4
#define PP 100

// tT slice layout per combo (tab,i0,i1), 1 KB, s-major:
//   addr(s, ab) = s*32 + ab*2   (bf16; uint at s*32 + k*4 packs ab=2k | ab=2k+1<<16)
// Phase2 lane sg reads 64 B at sg*64 = rows s=2sg, s=2sg+1.

__device__ __forceinline__ uint32_t f2bf(float f) {
    union { float f; uint32_t u; } v; v.f = f;
    uint32_t u = v.u;
    return (u + 0x7fffu + ((u >> 16) & 1u)) >> 16;   // RNE to bf16
}

// ---------------- Phase 1: t[tab,i0,i1] = c0[tab,i0] @ c1[tab,i1] ----------------
// grid: 4 tab * 100 i1 * 7 chunks(16 i0) = 2800 blocks, 128 threads.
// thread (u 0..7, sg 0..15): 2 i0 (2u,2u+1), s-pair (2sg,2sg+1), all 16 ab.
// per r: 1 ds_read_b128 x2 (c0, reused over 32 s-FMAs) + 4 ds_read_b64 (c1) -> 64 FMA.
__global__ __launch_bounds__(128, 3)
void tt_phase1(const float* __restrict__ c0g, const float* __restrict__ c1g,
               unsigned short* __restrict__ tT) {
    __shared__ float c1s[32 * 128];   // [r][b*32+s]  (natural layout)
    __shared__ float c0t[16 * 132];   // [i0l][r*4+a] (padded stride)

    int blk = blockIdx.x;
    int tab   = blk / 700;
    int rem   = blk % 700;
    int i1    = rem / 7;
    int chunk = rem % 7;
    int i0_base = chunk * 16;
    int tid = threadIdx.x;

    // stage c1 slice (16 KB), linear copy
    const float4* c1p = (const float4*)(c1g + (size_t)(tab * PP + i1) * 4096);
    float4* c1v = (float4*)c1s;
    #pragma unroll
    for (int it = 0; it < 8; ++it) c1v[tid + 128 * it] = c1p[tid + 128 * it];

    // stage c0 transposed: c0t[i0l][r*4+a] = c0[i0][a*32+r]
    #pragma unroll
    for (int it = 0; it < 16; ++it) {
        int f = tid + 128 * it;          // 0..2047
        int i0l = f >> 7;
        int x   = f & 127;               // a*32 + r
        int a = x >> 5, r = x & 31;
        int i0 = i0_base + i0l; if (i0 > PP - 1) i0 = PP - 1;
        c0t[i0l * 132 + r * 4 + a] = c0g[(size_t)(tab * PP + i0) * 128 + x];
    }
    __syncthreads();

    int u  = tid >> 4;                   // 0..7
    int sg = tid & 15;

    float acc[2][2][16];                 // [i0 sel][e (s parity)][ab]
    #pragma unroll
    for (int ii = 0; ii < 2; ++ii)
        #pragma unroll
        for (int e = 0; e < 2; ++e)
            #pragma unroll
            for (int q = 0; q < 16; ++q) acc[ii][e][q] = 0.f;

    #pragma unroll 4
    for (int r = 0; r < 32; ++r) {
        float4 av0 = *(const float4*)&c0t[(2 * u) * 132 + r * 4];
        float4 av1 = *(const float4*)&c0t[(2 * u + 1) * 132 + r * 4];
        const float* a0 = (const float*)&av0;
        const float* a1 = (const float*)&av1;
        #pragma unroll
        for (int b = 0; b < 4; ++b) {
            float2 bv = *(const float2*)&c1s[r * 128 + b * 32 + 2 * sg];
            #pragma unroll
            for (int a = 0; a < 4; ++a) {
                acc[0][0][a * 4 + b] += a0[a] * bv.x;
                acc[0][1][a * 4 + b] += a0[a] * bv.y;
                acc[1][0][a * 4 + b] += a1[a] * bv.x;
                acc[1][1][a * 4 + b] += a1[a] * bv.y;
            }
        }
    }

    #pragma unroll
    for (int ii = 0; ii < 2; ++ii) {
        int i0 = i0_base + 2 * u + ii;
        if (i0 >= PP) continue;
        size_t combo = (size_t)tab * 10000 + (size_t)i0 * 100 + (size_t)i1;
        char* base = (char*)tT + combo * 1024 + (size_t)sg * 64;
        #pragma unroll
        for (int e = 0; e < 2; ++e) {       // s = 2sg + e, 32 B row = 2 uint4
            uint4 w0, w1;
            w0.x = f2bf(acc[ii][e][0])  | (f2bf(acc[ii][e][1])  << 16);
            w0.y = f2bf(acc[ii][e][2])  | (f2bf(acc[ii][e][3])  << 16);
            w0.z = f2bf(acc[ii][e][4])  | (f2bf(acc[ii][e][5])  << 16);
            w0.w = f2bf(acc[ii][e][6])  | (f2bf(acc[ii][e][7])  << 16);
            w1.x = f2bf(acc[ii][e][8])  | (f2bf(acc[ii][e][9])  << 16);
            w1.y = f2bf(acc[ii][e][10]) | (f2bf(acc[ii][e][11]) << 16);
            w1.z = f2bf(acc[ii][e][12]) | (f2bf(acc[ii][e][13]) << 16);
            w1.w = f2bf(acc[ii][e][14]) | (f2bf(acc[ii][e][15]) << 16);
            *(uint4*)(base + e * 32)      = w0;
            *(uint4*)(base + e * 32 + 16) = w1;
        }
    }
}

// ---------------- Phase 2: gather tT + contract with c2 + pool ----------------
// 1 wave per bag, 4 waves/block. lane = (sub 0..3, sg 0..15): lookup slots
// sub, sub+4, sub+8, sub+12; s-pair 2sg,2sg+1. 24 fully-independent VMEM loads
// (16x uint4 t + 8x float4 c2, every instr 1 KB unique data) issued up-front;
// acc[64] partials; 64-lane fold leaves output[lane] in acc[0].
__global__ __launch_bounds__(256, 2)
void tt_phase2(const int* __restrict__ indices, const int* __restrict__ offsets,
               const unsigned short* __restrict__ tT, const float* __restrict__ c2g,
               float* __restrict__ out, int bags_per_table, int B) {
    int lane = threadIdx.x & 63;
    int wv   = threadIdx.x >> 6;
    int bag  = blockIdx.x * 4 + wv;
    if (bag >= B) return;
    int sub = lane >> 4;
    int sg  = lane & 15;
    int tab = bag / bags_per_table;
    int start = offsets[bag];

    const float* c2t = c2g + (size_t)tab * PP * 128;

    const uint4*  tp[4];
    const float4* cp[4];
    #pragma unroll
    for (int j = 0; j < 4; ++j) {
        uint32_t idx = (uint32_t)indices[start + j * 4 + sub];
        uint32_t i0 = idx / 10000u;
        uint32_t r1 = idx - i0 * 10000u;
        uint32_t i1 = r1 / 100u;
        uint32_t i2 = r1 - i1 * 100u;
        tp[j] = (const uint4*)((const char*)tT +
                 ((size_t)tab * 10000u + i0 * 100u + i1) * 1024 + (size_t)sg * 64);
        cp[j] = (const float4*)(c2t + (size_t)i2 * 128 + sg * 8);
    }

    uint4  T[4][4];
    float4 C[4][2];
    #pragma unroll
    for (int j = 0; j < 4; ++j) {
        T[j][0] = tp[j][0]; T[j][1] = tp[j][1];
        T[j][2] = tp[j][2]; T[j][3] = tp[j][3];
        C[j][0] = cp[j][0]; C[j][1] = cp[j][1];
    }

    float acc[64];
    #pragma unroll
    for (int d = 0; d < 64; ++d) acc[d] = 0.f;

    #pragma unroll
    for (int j = 0; j < 4; ++j) {
        #pragma unroll
        for (int e = 0; e < 2; ++e) {        // s = 2sg + e
            float4 cv = C[j][e];
            uint32_t us[8] = { T[j][2*e].x, T[j][2*e].y, T[j][2*e].z, T[j][2*e].w,
                               T[j][2*e+1].x, T[j][2*e+1].y, T[j][2*e+1].z, T[j][2*e+1].w };
            #pragma unroll
            for (int k = 0; k < 8; ++k) {    // ab = 2k, 2k+1
                float f0 = __uint_as_float(us[k] << 16);
                float f1 = __uint_as_float(us[k] & 0xffff0000u);
                int d0 = (2 * k) * 4, d1 = d0 + 4;
                acc[d0 + 0] += f0 * cv.x;  acc[d0 + 1] += f0 * cv.y;
                acc[d0 + 2] += f0 * cv.z;  acc[d0 + 3] += f0 * cv.w;
                acc[d1 + 0] += f1 * cv.x;  acc[d1 + 1] += f1 * cv.y;
                acc[d1 + 2] += f1 * cv.z;  acc[d1 + 3] += f1 * cv.w;
            }
        }
    }

    // fold-reduce across 64 lanes; lane l ends with output element l in acc[0]
    #pragma unroll
    for (int m = 32; m >= 1; m >>= 1) {
        bool up = (lane & m) != 0;
        #pragma unroll
        for (int j = 0; j < m; ++j) {
            float lo = acc[j], hi = acc[j + m];
            float send = up ? lo : hi;
            float recv = __shfl_xor(send, m, 64);
            acc[j] = (up ? hi : lo) + recv;
        }
    }
    out[(size_t)bag * 64 + lane] = acc[0];
}

extern "C" void kernel_launch(void* const* d_in, const int* in_sizes, int n_in,
                              void* d_out, int out_size, void* d_ws, size_t ws_size,
                              hipStream_t stream) {
    const int*   indices = (const int*)d_in[0];
    const int*   offsets = (const int*)d_in[1];
    const float* c0      = (const float*)d_in[2];
    const float* c1      = (const float*)d_in[3];
    const float* c2      = (const float*)d_in[4];
    float* out = (float*)d_out;

    int B = in_sizes[1] - 1;              // 32768 bags
    int bags_per_table = B / NT;          // 8192

    unsigned short* tT = (unsigned short*)d_ws;   // 40.96 MB

    tt_phase1<<<dim3(NT * PP * 7), dim3(128), 0, stream>>>(c0, c1, tT);
    tt_phase2<<<dim3((B + 3) / 4), dim3(256), 0, stream>>>(indices, offsets, tT, c2, out,
                                                           bags_per_table, B);
}

// Round 4
// 155.117 us; speedup vs baseline: 2.4483x; 1.0733x over previous
//
#include <hip/hip_runtime.h>
#include <stdint.h>

#define NT 4
#define PP 100
#define TT_BYTES (4ull * 100 * 100 * 1024)   // 40,960,000 B for tT in d_ws

// tT layout per combo (tab,i0,i1), 1 KB: dword at byte sg*64 + ab*4 packs
//   lo = bf16 t[ab][s=2sg], hi = bf16 t[ab][s=2sg+1]   (sg 0..15, ab 0..15)
// c2p layout (after tT in d_ws): uint4 per (tab,i2,sg): dwords c=0..3, each
//   lo = bf16 c2[2sg][c], hi = bf16 c2[2sg+1][c]

__device__ __forceinline__ uint32_t f2bf(float f) {
    union { float f; uint32_t u; } v; v.f = f;
    uint32_t u = v.u;
    return (u + 0x7fffu + ((u >> 16) & 1u)) >> 16;   // RNE to bf16
}

// v_dot2_f32_bf16: d = a.lo*b.lo + a.hi*b.hi + c   (bf16 pairs, f32 acc)
__device__ __forceinline__ float dot2bf(uint32_t a, uint32_t b, float c) {
    float d;
    asm("v_dot2_f32_bf16 %0, %1, %2, %3" : "=v"(d) : "v"(a), "v"(b), "v"(c));
    return d;
}

// ---------------- Phase 0: pack c2 into bf16 s-pair dwords ----------------
__global__ __launch_bounds__(256)
void c2pack_kernel(const float* __restrict__ c2g, uint32_t* __restrict__ c2p) {
    int t = blockIdx.x * 256 + threadIdx.x;       // ((tab*100+i2)*16+sg)*4 + c
    if (t >= NT * PP * 64) return;
    int c = t & 3, sg = (t >> 2) & 15, rest = t >> 6;
    int i2 = rest % PP, tab = rest / PP;
    const float* src = c2g + (size_t)(tab * PP + i2) * 128;
    float e = src[(2 * sg) * 4 + c];
    float o = src[(2 * sg + 1) * 4 + c];
    c2p[t] = f2bf(e) | (f2bf(o) << 16);
}

// ---------------- Phase 1: t[tab,i0,i1] = c0[tab,i0] @ c1[tab,i1] ----------------
// grid: 4 tab * 100 i1 * 7 chunks(16 i0) = 2800 blocks, 128 threads.
// thread (u 0..7, sg 0..15): 2 i0 (2u,2u+1), s-pair (2sg,2sg+1), all 16 ab.
__global__ __launch_bounds__(128, 3)
void tt_phase1(const float* __restrict__ c0g, const float* __restrict__ c1g,
               unsigned short* __restrict__ tT) {
    __shared__ float c1s[32 * 128];   // [r][b*32+s]
    __shared__ float c0t[16 * 132];   // [i0l][r*4+a] (padded stride)

    int blk = blockIdx.x;
    int tab   = blk / 700;
    int rem   = blk % 700;
    int i1    = rem / 7;
    int chunk = rem % 7;
    int i0_base = chunk * 16;
    int tid = threadIdx.x;

    const float4* c1p = (const float4*)(c1g + (size_t)(tab * PP + i1) * 4096);
    float4* c1v = (float4*)c1s;
    #pragma unroll
    for (int it = 0; it < 8; ++it) c1v[tid + 128 * it] = c1p[tid + 128 * it];

    #pragma unroll
    for (int it = 0; it < 16; ++it) {
        int f = tid + 128 * it;          // 0..2047
        int i0l = f >> 7;
        int x   = f & 127;               // a*32 + r
        int a = x >> 5, r = x & 31;
        int i0 = i0_base + i0l; if (i0 > PP - 1) i0 = PP - 1;
        c0t[i0l * 132 + r * 4 + a] = c0g[(size_t)(tab * PP + i0) * 128 + x];
    }
    __syncthreads();

    int u  = tid >> 4;                   // 0..7
    int sg = tid & 15;

    float acc[2][2][16];                 // [i0 sel][e (s parity)][ab]
    #pragma unroll
    for (int ii = 0; ii < 2; ++ii)
        #pragma unroll
        for (int e = 0; e < 2; ++e)
            #pragma unroll
            for (int q = 0; q < 16; ++q) acc[ii][e][q] = 0.f;

    #pragma unroll 4
    for (int r = 0; r < 32; ++r) {
        float4 av0 = *(const float4*)&c0t[(2 * u) * 132 + r * 4];
        float4 av1 = *(const float4*)&c0t[(2 * u + 1) * 132 + r * 4];
        const float* a0 = (const float*)&av0;
        const float* a1 = (const float*)&av1;
        #pragma unroll
        for (int b = 0; b < 4; ++b) {
            float2 bv = *(const float2*)&c1s[r * 128 + b * 32 + 2 * sg];
            #pragma unroll
            for (int a = 0; a < 4; ++a) {
                acc[0][0][a * 4 + b] += a0[a] * bv.x;
                acc[0][1][a * 4 + b] += a0[a] * bv.y;
                acc[1][0][a * 4 + b] += a1[a] * bv.x;
                acc[1][1][a * 4 + b] += a1[a] * bv.y;
            }
        }
    }

    #pragma unroll
    for (int ii = 0; ii < 2; ++ii) {
        int i0 = i0_base + 2 * u + ii;
        if (i0 >= PP) continue;
        size_t combo = (size_t)tab * 10000 + (size_t)i0 * 100 + (size_t)i1;
        char* base = (char*)tT + combo * 1024 + (size_t)sg * 64;  // lane's own 64B line
        #pragma unroll
        for (int k = 0; k < 4; ++k) {    // dwords ab = 4k..4k+3
            uint4 w;
            w.x = f2bf(acc[ii][0][4*k+0]) | (f2bf(acc[ii][1][4*k+0]) << 16);
            w.y = f2bf(acc[ii][0][4*k+1]) | (f2bf(acc[ii][1][4*k+1]) << 16);
            w.z = f2bf(acc[ii][0][4*k+2]) | (f2bf(acc[ii][1][4*k+2]) << 16);
            w.w = f2bf(acc[ii][0][4*k+3]) | (f2bf(acc[ii][1][4*k+3]) << 16);
            *(uint4*)(base + k * 16) = w;
        }
    }
}

// ---------------- Phase 2: gather tT + dot2 with packed c2 + pool ----------------
// 1 wave per bag, 4 waves/block. lane = (sub 0..3, sg 0..15). All 20 VMEM
// loads (16 uint4 t + 4 uint4 c2p) issued up-front; 256 v_dot2_f32_bf16;
// acc[64] partials; 64-lane fold leaves output[lane] in acc[0].
__global__ __launch_bounds__(256, 3)
void tt_phase2(const int* __restrict__ indices, const int* __restrict__ offsets,
               const unsigned short* __restrict__ tT, const uint32_t* __restrict__ c2p,
               float* __restrict__ out, int bags_per_table, int B) {
    int lane = threadIdx.x & 63;
    int wv   = threadIdx.x >> 6;
    int bag  = blockIdx.x * 4 + wv;
    if (bag >= B) return;
    int sub = lane >> 4;
    int sg  = lane & 15;
    int tab = bag / bags_per_table;
    int start = offsets[bag];

    const uint4* c2q = (const uint4*)c2p;

    const uint4* tp[4];
    int ci[4];
    #pragma unroll
    for (int j = 0; j < 4; ++j) {
        uint32_t idx = (uint32_t)indices[start + j * 4 + sub];
        uint32_t i0 = idx / 10000u;
        uint32_t r1 = idx - i0 * 10000u;
        uint32_t i1 = r1 / 100u;
        uint32_t i2 = r1 - i1 * 100u;
        tp[j] = (const uint4*)((const char*)tT +
                 ((size_t)tab * 10000u + i0 * 100u + i1) * 1024 + (size_t)sg * 64);
        ci[j] = (tab * PP + (int)i2) * 16 + sg;
    }

    uint4 T[4][4];
    uint4 C[4];
    #pragma unroll
    for (int j = 0; j < 4; ++j) {
        T[j][0] = tp[j][0]; T[j][1] = tp[j][1];
        T[j][2] = tp[j][2]; T[j][3] = tp[j][3];
        C[j] = c2q[ci[j]];
    }

    float acc[64];
    #pragma unroll
    for (int d = 0; d < 64; ++d) acc[d] = 0.f;

    #pragma unroll
    for (int j = 0; j < 4; ++j) {
        uint32_t cd[4] = { C[j].x, C[j].y, C[j].z, C[j].w };
        #pragma unroll
        for (int k = 0; k < 4; ++k) {
            uint32_t td[4] = { T[j][k].x, T[j][k].y, T[j][k].z, T[j][k].w };
            #pragma unroll
            for (int m = 0; m < 4; ++m) {     // ab = 4k + m
                int d0 = (4 * k + m) * 4;
                acc[d0 + 0] = dot2bf(td[m], cd[0], acc[d0 + 0]);
                acc[d0 + 1] = dot2bf(td[m], cd[1], acc[d0 + 1]);
                acc[d0 + 2] = dot2bf(td[m], cd[2], acc[d0 + 2]);
                acc[d0 + 3] = dot2bf(td[m], cd[3], acc[d0 + 3]);
            }
        }
    }

    // fold-reduce across 64 lanes; lane l ends with output element l in acc[0]
    #pragma unroll
    for (int m = 32; m >= 1; m >>= 1) {
        bool up = (lane & m) != 0;
        #pragma unroll
        for (int j = 0; j < m; ++j) {
            float lo = acc[j], hi = acc[j + m];
            float send = up ? lo : hi;
            float recv = __shfl_xor(send, m, 64);
            acc[j] = (up ? hi : lo) + recv;
        }
    }
    out[(size_t)bag * 64 + lane] = acc[0];
}

extern "C" void kernel_launch(void* const* d_in, const int* in_sizes, int n_in,
                              void* d_out, int out_size, void* d_ws, size_t ws_size,
                              hipStream_t stream) {
    const int*   indices = (const int*)d_in[0];
    const int*   offsets = (const int*)d_in[1];
    const float* c0      = (const float*)d_in[2];
    const float* c1      = (const float*)d_in[3];
    const float* c2      = (const float*)d_in[4];
    float* out = (float*)d_out;

    int B = in_sizes[1] - 1;              // 32768 bags
    int bags_per_table = B / NT;          // 8192

    unsigned short* tT  = (unsigned short*)d_ws;
    uint32_t*       c2p = (uint32_t*)((char*)d_ws + TT_BYTES);   // +100 KB

    c2pack_kernel<<<dim3((NT * PP * 64 + 255) / 256), dim3(256), 0, stream>>>(c2, c2p);
    tt_phase1<<<dim3(NT * PP * 7), dim3(128), 0, stream>>>(c0, c1, tT);
    tt_phase2<<<dim3((B + 3) / 4), dim3(256), 0, stream>>>(indices, offsets, tT, c2p, out,
                                                           bags_per_table, B);
}